// Round 14
// baseline (224.871 us; speedup 1.0000x reference)
//
#include <hip/hip_runtime.h>
#include <stdint.h>

#define B_ 32
#define T_ 4096
#define D_ 512
#define BT_ (B_*T_)
#define ROWS_ 128         // rows per block
#define NBLK_ (BT_/ROWS_) // 1024

typedef __attribute__((ext_vector_type(8))) short bf16x8;
typedef __attribute__((ext_vector_type(4))) float f32x4;

__device__ __forceinline__ unsigned short f2bf(float f) {
    unsigned int u = __float_as_uint(f);
    u += 0x7FFFu + ((u >> 16) & 1u);   // round-to-nearest-even (inputs are finite)
    return (unsigned short)(u >> 16);
}

__device__ __forceinline__ unsigned pk2(float a, float b) {
    return (unsigned)f2bf(a) | ((unsigned)f2bf(b) << 16);   // low16 = a, high16 = b
}

__device__ __forceinline__ float tanh_fast(float x) {
    float e2 = __expf(2.0f * x);
    return 1.0f - 2.0f / (e2 + 1.0f);
}

// async global->LDS DMA, 16B per lane. LDS dest = wave-uniform base + lane*16;
// global src = per-lane address; offset arg always 0 (R9-validated semantics).
__device__ __forceinline__ void gl16(const void* g, const void* lds) {
    __builtin_amdgcn_global_load_lds(
        (const __attribute__((address_space(1))) void*)g,
        (__attribute__((address_space(3))) void*)lds, 16, 0, 0);
}

#define WAITVM(N) asm volatile("s_waitcnt vmcnt(" #N ")" ::: "memory")

// ---------------------------------------------------------------------------
// W_h (D x D fp32, [k][n]) -> bf16 MFMA B-fragment layout in ws (unchanged).
__global__ __launch_bounds__(256) void k_conv_wh(const float* __restrict__ W_h,
                                                 unsigned short* __restrict__ wsb) {
    int tid = blockIdx.x * 256 + threadIdx.x;
    int l  = tid & 63;
    int kt = (tid >> 6) & 15;
    int nt = tid >> 10;
    int n  = nt * 16 + (l & 15);
    int k0 = kt * 32 + (l >> 4) * 8;
    unsigned int w[4];
#pragma unroll
    for (int q = 0; q < 4; ++q) {
        unsigned short lo = f2bf(W_h[(size_t)(k0 + 2*q)     * D_ + n]);
        unsigned short hi = f2bf(W_h[(size_t)(k0 + 2*q + 1) * D_ + n]);
        w[q] = (unsigned int)lo | ((unsigned int)hi << 16);
    }
    uint4 pk = {w[0], w[1], w[2], w[3]};
    ((uint4*)wsb)[tid] = pk;
}

// ---------------------------------------------------------------------------
__global__ __launch_bounds__(256) void k_dec(const float* __restrict__ s_t,
                                             const float* __restrict__ W_s,
                                             const float* __restrict__ b_s,
                                             float* __restrict__ dec) {
    int b = blockIdx.x;
    int c = threadIdx.x;
    float a0 = b_s[c], a1 = b_s[c + 256];
    const float* srow = s_t + b * D_;
    for (int k = 0; k < D_; ++k) {
        float s = srow[k];
        const float* wr = W_s + (size_t)k * D_;
        a0 = fmaf(s, wr[c], a0);
        a1 = fmaf(s, wr[c + 256], a1);
    }
    dec[b * D_ + c] = a0;
    dec[b * D_ + c + 256] = a1;
}

// ---------------------------------------------------------------------------
// Main fused kernel: BM=128 x BN=512 x BK=32, 8 waves (512 thr),
// launch_bounds(512,2) -> 256-reg budget (acc 128 AGPR + ~60 VGPR, no spill).
// A (fp32) + B (bf16 frags from wsb) streamed to LDS via global_load_lds,
// 3 buffers x 48KB, 2 stages in flight, counted s_waitcnt vmcnt(6) (never 0
// in the main loop), one raw s_barrier per K-step.
//   buffer: A = 8 frags x 2KB fp32 (frag af: lane l -> row l&15, k (l>>4)*8,
//           chunk c holds k-j c*4..c*4+3 at c*1KB + l*16); B = 32 frags x 1KB.
// Wave w = (m = w>>2, n = w&3): rows m*64..+64, cols n*128..+128.
// Per step/wave: 8 A-reads(fp32->bf16 convert) + 8 B-reads -> 32 MFMA.
// Epilogue: tanh/V-dot fused; e_t full-width; context partial via global
// re-read of the block's 128 rows (A k-slices are not resident).
__global__ __launch_bounds__(512, 2) void k_main(const float* __restrict__ h_i,
                                                 const float* __restrict__ coverage,
                                                 const unsigned short* __restrict__ wsb,
                                                 const float* __restrict__ dec,
                                                 const float* __restrict__ W_c,
                                                 const float* __restrict__ V,
                                                 float* __restrict__ e_out,
                                                 float* __restrict__ part) {
    __shared__ __align__(16) unsigned char As[3 * 49152];   // 147456 B
    __shared__ float red[8][ROWS_];
    __shared__ float wexp[ROWS_];
    const int tid = threadIdx.x;
    const int w = tid >> 6, l = tid & 63;      // w: 0..7
    const int m = w >> 2, n = w & 3;
    const int row0 = blockIdx.x * ROWS_;
    const int b    = row0 >> 12;
    const int t0   = row0 & (T_ - 1);

    // staging source pointers (per lane)
    const float* gA = h_i + (size_t)(row0 + w * 16 + (l & 15)) * D_ + ((l >> 4) * 8);
    const char*  gB = (const char*)wsb + w * 65536 + l * 16;   // + i*16384 + t*1024

    // stage step t into buffer base bp: 2 A-gloads + 4 B-gloads per wave
#define STAGE(t, bp)  do {                                                    \
        gl16(gA + (t) * 32,     (bp) + w * 2048);                             \
        gl16(gA + (t) * 32 + 4, (bp) + w * 2048 + 1024);                      \
        gl16(gB + 0 * 16384 + (t) * 1024, (bp) + 16384 + (w * 4 + 0) * 1024); \
        gl16(gB + 1 * 16384 + (t) * 1024, (bp) + 16384 + (w * 4 + 1) * 1024); \
        gl16(gB + 2 * 16384 + (t) * 1024, (bp) + 16384 + (w * 4 + 2) * 1024); \
        gl16(gB + 3 * 16384 + (t) * 1024, (bp) + 16384 + (w * 4 + 3) * 1024); \
    } while (0)

    f32x4 acc[4][8];
#pragma unroll
    for (int af = 0; af < 4; ++af)
#pragma unroll
        for (int nt = 0; nt < 8; ++nt) acc[af][nt] = (f32x4){0, 0, 0, 0};

    unsigned char* buf0 = As;
    unsigned char* buf1 = As + 49152;
    unsigned char* buf2 = As + 98304;

    // compute one K-step from buffer base bp
#define COMPUTE(bp)  do {                                                     \
        uint4 braw[8];                                                        \
        _Pragma("unroll")                                                     \
        for (int nt = 0; nt < 8; ++nt)                                        \
            braw[nt] = *(const uint4*)((bp) + 16384 + (n * 8 + nt) * 1024 + l * 16); \
        _Pragma("unroll")                                                     \
        for (int af = 0; af < 4; ++af) {                                      \
            const unsigned char* ab = (bp) + (m * 4 + af) * 2048 + l * 16;    \
            float4 f0 = *(const float4*)ab;                                   \
            float4 f1 = *(const float4*)(ab + 1024);                          \
            uint4 a4 = {pk2(f0.x, f0.y), pk2(f0.z, f0.w),                     \
                        pk2(f1.x, f1.y), pk2(f1.z, f1.w)};                    \
            bf16x8 a = __builtin_bit_cast(bf16x8, a4);                        \
            _Pragma("unroll")                                                 \
            for (int nt = 0; nt < 8; ++nt)                                    \
                acc[af][nt] = __builtin_amdgcn_mfma_f32_16x16x32_bf16(        \
                    a, __builtin_bit_cast(bf16x8, braw[nt]), acc[af][nt], 0, 0, 0); \
        }                                                                     \
    } while (0)

    // ---- prologue: stages 0 and 1 in flight; wait own stage-0 (6 left)
    STAGE(0, buf0);
    STAGE(1, buf1);
    WAITVM(6);
    __builtin_amdgcn_s_barrier();
    __builtin_amdgcn_sched_barrier(0);

    // ---- main loop t = 0..13: stage t+2, compute t, counted wait, barrier
    {
        unsigned char* bcur = buf0;   // t   % 3
        unsigned char* bnxt = buf1;   // t+1 % 3
        unsigned char* bstg = buf2;   // t+2 % 3
#pragma unroll 1
        for (int t = 0; t < 14; ++t) {
            STAGE(t + 2, bstg);
            COMPUTE(bcur);
            WAITVM(6);                 // stage(t+1) done; stage(t+2) in flight
            __builtin_amdgcn_s_barrier();
            __builtin_amdgcn_sched_barrier(0);
            unsigned char* tmp = bcur; bcur = bnxt; bnxt = bstg; bstg = tmp;
        }
        // tail: t = 14 (buf rotation: bcur = buf14%3=2? -> tracked by pointers)
        COMPUTE(bcur);
        WAITVM(0);                     // stage(15) done
        __builtin_amdgcn_s_barrier();
        __builtin_amdgcn_sched_barrier(0);
        COMPUTE(bnxt);
    }

    // ---- epilogue: tanh + dot with V over this wave's 128 cols
    const int rgrp = (l >> 4) * 4;
    {
        float dv[8], wc8[8], vv8[8];
#pragma unroll
        for (int nt = 0; nt < 8; ++nt) {
            int col = n * 128 + nt * 16 + (l & 15);
            dv[nt]  = dec[b * D_ + col];
            wc8[nt] = W_c[col];
            vv8[nt] = V[col];
        }
#pragma unroll
        for (int af = 0; af < 4; ++af) {
            float pr[4];
#pragma unroll
            for (int r = 0; r < 4; ++r) {
                float cv = coverage[b * T_ + t0 + m * 64 + af * 16 + rgrp + r];
                float s = 0.f;
#pragma unroll
                for (int nt = 0; nt < 8; ++nt) {
                    float x = acc[af][nt][r] + dv[nt] + cv * wc8[nt];
                    s += tanh_fast(x) * vv8[nt];
                }
                pr[r] = s;
            }
#pragma unroll
            for (int mm = 1; mm <= 8; mm <<= 1)
#pragma unroll
                for (int r = 0; r < 4; ++r)
                    pr[r] += __shfl_xor(pr[r], mm, 64);
            if ((l & 15) == 0) {
#pragma unroll
                for (int r = 0; r < 4; ++r)
                    red[w][m * 64 + af * 16 + rgrp + r] = pr[r];
            }
        }
    }
    __syncthreads();
    if (tid < ROWS_) {
        int mg = tid >> 6;             // owning m-group
        float e = red[mg * 4 + 0][tid] + red[mg * 4 + 1][tid]
                + red[mg * 4 + 2][tid] + red[mg * 4 + 3][tid];
        e_out[b * T_ + t0 + tid] = e;
        wexp[tid] = __expf(e);
    }
    __syncthreads();

    // ---- context partial: re-read this block's 128 rows from global (L2/L3-hot).
    // thread: rg = tid>>7 (rows rg*32..+31), dq = tid&127 (float4 d-chunk).
    {
        const int rg = tid >> 7, dq = tid & 127;
        const float* hb = h_i + (size_t)(row0 + rg * 32) * D_ + dq * 4;
        float4 a0 = {0,0,0,0}, a1 = {0,0,0,0};
#pragma unroll 4
        for (int rr = 0; rr < 32; rr += 2) {
            float w0 = wexp[rg * 32 + rr];
            float w1 = wexp[rg * 32 + rr + 1];
            float4 h0 = *(const float4*)(hb + (size_t)rr * D_);
            float4 h1 = *(const float4*)(hb + (size_t)(rr + 1) * D_);
            a0.x = fmaf(w0, h0.x, a0.x); a0.y = fmaf(w0, h0.y, a0.y);
            a0.z = fmaf(w0, h0.z, a0.z); a0.w = fmaf(w0, h0.w, a0.w);
            a1.x = fmaf(w1, h1.x, a1.x); a1.y = fmaf(w1, h1.y, a1.y);
            a1.z = fmaf(w1, h1.z, a1.z); a1.w = fmaf(w1, h1.w, a1.w);
        }
        a0.x += a1.x; a0.y += a1.y; a0.z += a1.z; a0.w += a1.w;
        float4* ctxred = (float4*)As;  // reuse GEMM LDS (free after last step)
        ctxred[rg * 128 + dq] = a0;
    }
    __syncthreads();
    if (tid < 128) {
        const float4* ctxred = (const float4*)As;
        float4 s0 = ctxred[tid], s1 = ctxred[128 + tid],
               s2 = ctxred[256 + tid], s3 = ctxred[384 + tid];
        float4 o;
        o.x = (s0.x + s1.x) + (s2.x + s3.x);
        o.y = (s0.y + s1.y) + (s2.y + s3.y);
        o.z = (s0.z + s1.z) + (s2.z + s3.z);
        o.w = (s0.w + s1.w) + (s2.w + s3.w);
        *(float4*)(part + (size_t)blockIdx.x * D_ + tid * 4) = o;
    }
}

// ---------------------------------------------------------------------------
__global__ __launch_bounds__(256) void k_soft(const float* __restrict__ e_in,
                                              const float* __restrict__ coverage,
                                              float* __restrict__ out_at,
                                              float* __restrict__ out_cov,
                                              float* __restrict__ Sb) {
    int b = blockIdx.x, tid = threadIdx.x;
    __shared__ float red[4];
    float v[16];
    float m = -1e30f;
#pragma unroll
    for (int i = 0; i < 16; ++i) {
        v[i] = e_in[b * T_ + tid + i * 256];
        m = fmaxf(m, v[i]);
    }
#pragma unroll
    for (int mk = 1; mk <= 32; mk <<= 1) m = fmaxf(m, __shfl_xor(m, mk, 64));
    if ((tid & 63) == 0) red[tid >> 6] = m;
    __syncthreads();
    m = fmaxf(fmaxf(red[0], red[1]), fmaxf(red[2], red[3]));
    float s = 0.f;
#pragma unroll
    for (int i = 0; i < 16; ++i) { v[i] = expf(v[i] - m); s += v[i]; }
#pragma unroll
    for (int mk = 1; mk <= 32; mk <<= 1) s += __shfl_xor(s, mk, 64);
    __syncthreads();
    if ((tid & 63) == 0) red[tid >> 6] = s;
    __syncthreads();
    s = red[0] + red[1] + red[2] + red[3];
    if (tid == 0) Sb[b] = __expf(m) * s;
    float inv = 1.0f / s;
#pragma unroll
    for (int i = 0; i < 16; ++i) {
        int idx = b * T_ + tid + i * 256;
        float a = v[i] * inv;
        out_at[idx]  = a;
        out_cov[idx] = coverage[idx] + a;
    }
}

// ---------------------------------------------------------------------------
// combine: context[b][d] = (sum_{s=0..31} part[(b*32+s)][d]) / S_b
__global__ __launch_bounds__(256) void k_comb(const float* __restrict__ part,
                                              const float* __restrict__ Sb,
                                              float* __restrict__ out_ctx) {
    int idx = blockIdx.x * 256 + threadIdx.x;
    int b = idx >> 9, d = idx & 511;
    const float* pp = part + (size_t)b * 32 * D_ + d;
    float s = 0.f;
#pragma unroll 8
    for (int j = 0; j < 32; ++j) s += pp[(size_t)j * D_];
    out_ctx[idx] = s / Sb[b];
}

// ---------------------------------------------------------------------------
extern "C" void kernel_launch(void* const* d_in, const int* in_sizes, int n_in,
                              void* d_out, int out_size, void* d_ws, size_t ws_size,
                              hipStream_t stream) {
    const float* h_i      = (const float*)d_in[0];
    const float* s_t      = (const float*)d_in[1];
    const float* coverage = (const float*)d_in[2];
    const float* W_h      = (const float*)d_in[3];
    const float* W_s      = (const float*)d_in[4];
    const float* b_s      = (const float*)d_in[5];
    const float* W_c      = (const float*)d_in[6];
    const float* V        = (const float*)d_in[7];

    float* out_ctx = (float*)d_out;             // B*D
    float* out_at  = out_ctx + B_ * D_;         // B*T (e_t between k_main and k_soft)
    float* out_cov = out_at + BT_;              // B*T

    unsigned short* wsb = (unsigned short*)d_ws;              // 512 KB bf16 W_h frags
    float* dec  = (float*)((char*)d_ws + 524288);             // 64 KB
    float* part = dec + B_ * D_;                              // 2 MB (1024 x 512 fp32)
    float* Sb   = part + (size_t)NBLK_ * D_;                  // 32 floats

    k_conv_wh<<<128, 256, 0, stream>>>(W_h, wsb);
    k_dec<<<B_, 256, 0, stream>>>(s_t, W_s, b_s, dec);
    k_main<<<NBLK_, 512, 0, stream>>>(h_i, coverage, wsb, dec, W_c, V, out_at, part);
    k_soft<<<B_, 256, 0, stream>>>(out_at, coverage, out_at, out_cov, Sb);
    k_comb<<<B_ * D_ / 256, 256, 0, stream>>>(part, Sb, out_ctx);
}